// Round 10
// baseline (105.048 us; speedup 1.0000x reference)
//
#include <hip/hip_runtime.h>
#include <math.h>

#define NCLS 16
#define TS   64      // pair-tile side (64x64 pairs per work item)
#define CH   32      // D-chunk depth
#define PAD  36      // 144 B row pitch: every row 16B-aligned for ds_read_b128
#define NB   512
#define PIXB 16      // pixels per norm block

// global float4 loads at 4-byte-aligned addresses (class start is arbitrary)
typedef float vfloat4 __attribute__((ext_vector_type(4), aligned(4)));

struct Ctl {
    int   counts[NCLS];
    int   starts[NCLS + 1];
    int   tpc[NCLS];          // tiles per class dimension = ceil(n/TS)
    int   pairBase[NCLS + 1]; // prefix sum of tpc^2
    float classSum[NCLS];
};

// ---------------- Kernel 1: norms (16 px/block, 257 blocks) + ctl -----------
// gt is SORTED -> class boundaries via binary search; contiguous segments == classes.
__global__ __launch_bounds__(256) void prep_kernel(
    const float* __restrict__ P, const float* __restrict__ T,
    const int* __restrict__ gt, int V, int D,
    Ctl* __restrict__ ctl,
    float* __restrict__ normP, float* __restrict__ normT,
    int nbNorm) {
    const int b = blockIdx.x;
    const int t = threadIdx.x;
    if (b < nbNorm) {
        __shared__ float pP[16][PIXB + 1], pT[16][PIXB + 1];
        const int pix = t & (PIXB - 1);
        const int dl  = t >> 4;           // 0..15
        const int v   = b * PIXB + pix;
        float np = 0.f, nt = 0.f;
        if (v < V) {
            #pragma unroll 4
            for (int d = dl; d < D; d += 16) {
                float x = P[(long)d * V + v]; np += x * x;
                float y = T[(long)d * V + v]; nt += y * y;
            }
        }
        pP[dl][pix] = np; pT[dl][pix] = nt;
        __syncthreads();
        if (t < PIXB && b * PIXB + t < V) {
            float sp = 0.f, st = 0.f;
            #pragma unroll
            for (int k = 0; k < 16; ++k) { sp += pP[k][t]; st += pT[k][t]; }
            normP[b * PIXB + t] = sp;
            normT[b * PIXB + t] = st;
        }
    } else {
        if (t < NCLS) {
            int lo = 0, hi = V;            // lower_bound of class id t
            while (lo < hi) {
                int mid = (lo + hi) >> 1;
                if (gt[mid] < t) lo = mid + 1; else hi = mid;
            }
            ctl->starts[t] = lo;
            ctl->classSum[t] = 0.0f;       // ws is poisoned 0xAA each replay
        }
        if (t == 0) ctl->starts[NCLS] = V;
        __syncthreads();
        if (t == 0) {
            int pb = 0;
            for (int c = 0; c < NCLS; ++c) {
                int n = ctl->starts[c + 1] - ctl->starts[c];
                ctl->counts[c] = n;
                int tp = (n + TS - 1) / TS;
                ctl->tpc[c] = tp;
                ctl->pairBase[c] = pb;
                pb += tp * tp;
            }
            ctl->pairBase[NCLS] = pb;
        }
    }
}

// ---------------- Kernel 2: 64x64 pair tiles, 4x4 per thread ----------------
// dist(i,j) = n_i + n_j - 2<x_i,x_j>  (Gram form, matches reference numerics).
// Staging tail rule: a quad is vector-loaded ONLY if fully inside the class;
// otherwise per-element clamp to pixel n-1 (rows r<n always hold pixel r's
// data -- RBF exp amplifies any norm/dot mismatch; rows >= n are masked).
// R9: `#pragma unroll 1` on dc/dg loops bounds the scheduler's hoisting
// window -> no spill (R7/R8 hit 256 VGPR + 60-105 MB scratch from full
// unroll). R10: within one dg iteration, ALL 16 ds_read_b128 issue up front
// (single lgkm wait point, 16 reads in flight) instead of R9's 3 dependent
// read->wait->FMA phases; at ~1 wave/SIMD every extra wait was ~120 cyc of
// fully exposed LDS latency. Safe only BECAUSE unroll stays 1.
__global__ __launch_bounds__(256) void mmd_kernel(
    const float* __restrict__ P, const float* __restrict__ T,
    int V, int D, const Ctl* __restrict__ ctl,
    const float* __restrict__ normP, const float* __restrict__ normT,
    float* __restrict__ classSum)
{
    __shared__ float sPr[TS][PAD], sTr[TS][PAD];
    __shared__ float sPc[TS][PAD], sTc[TS][PAD];
    __shared__ float wsum[4];

    const int t  = threadIdx.x;
    const int tx = t & 15;   // cols tx + 16b, b=0..3
    const int ty = t >> 4;   // rows ty + 16a, a=0..3
    const int sd = t >> 3;   // staging dim 0..31
    const int qb = t & 7;    // staging pixel-quad base: quads qb and qb+8
    const int W  = ctl->pairBase[NCLS];

    const float invs[6] = {-0.25f, -0.1f, -0.05f, -0.025f, -0.0125f, -1.0f/120.0f};

    for (int w = blockIdx.x; w < W; w += gridDim.x) {
        int c = 0;
        while (ctl->pairBase[c + 1] <= w) ++c;
        const int local = w - ctl->pairBase[c];
        const int tp    = ctl->tpc[c];
        const int ti    = local / tp;
        const int tj    = local - ti * tp;
        const int n     = ctl->counts[c];
        const int start = ctl->starts[c];
        const int i0    = ti * TS;
        const int j0    = tj * TS;

        // relative quad bases within the class
        const int r0 = i0 + 4 * qb;
        const int r1 = i0 + 4 * qb + 32;
        const int c0 = j0 + 4 * qb;
        const int c1 = j0 + 4 * qb + 32;

        vfloat4 vPr0, vPr1, vTr0, vTr1, vPc0, vPc1, vTc0, vTc1;

        auto load_quad = [&](long off, int rb, vfloat4& vP, vfloat4& vT) {
            if (rb + 3 < n) {
                vP = *(const vfloat4*)&P[off + start + rb];
                vT = *(const vfloat4*)&T[off + start + rb];
            } else {
                int a0 = start + min(rb,     n - 1);
                int a1 = start + min(rb + 1, n - 1);
                int a2 = start + min(rb + 2, n - 1);
                int a3 = start + min(rb + 3, n - 1);
                vP = (vfloat4){P[off + a0], P[off + a1], P[off + a2], P[off + a3]};
                vT = (vfloat4){T[off + a0], T[off + a1], T[off + a2], T[off + a3]};
            }
        };
        auto issue_loads = [&](int dcc) {
            const long off = (long)(dcc + sd) * (long)V;
            load_quad(off, r0, vPr0, vTr0);
            load_quad(off, r1, vPr1, vTr1);
            load_quad(off, c0, vPc0, vTc0);
            load_quad(off, c1, vPc1, vTc1);
        };

        float dpp[4][4], dtt[4][4], dpt[4][4];
        #pragma unroll
        for (int a = 0; a < 4; ++a)
            #pragma unroll
            for (int b = 0; b < 4; ++b) { dpp[a][b] = 0.f; dtt[a][b] = 0.f; dpt[a][b] = 0.f; }

        issue_loads(0);

        #pragma unroll 1
        for (int dc = 0; dc < D; dc += CH) {
            __syncthreads();   // previous chunk's LDS reads (and wsum) complete
            #pragma unroll
            for (int k = 0; k < 4; ++k) {
                sPr[4*qb +      k][sd] = vPr0[k];
                sPr[4*qb + 32 + k][sd] = vPr1[k];
                sTr[4*qb +      k][sd] = vTr0[k];
                sTr[4*qb + 32 + k][sd] = vTr1[k];
                sPc[4*qb +      k][sd] = vPc0[k];
                sPc[4*qb + 32 + k][sd] = vPc1[k];
                sTc[4*qb +      k][sd] = vTc0[k];
                sTc[4*qb + 32 + k][sd] = vTc1[k];
            }
            __syncthreads();
            if (dc + CH < D)
                issue_loads(dc + CH);   // prefetch next chunk; overlaps compute

            // NOT unrolled; all 16 reads issue before any FMA (one wait point)
            #pragma unroll 1
            for (int dg = 0; dg < CH; dg += 4) {
                float4 rP[4], rT[4], cP[4], cT[4];
                #pragma unroll
                for (int a = 0; a < 4; ++a) {
                    rP[a] = *(const float4*)&sPr[ty + 16*a][dg];
                    rT[a] = *(const float4*)&sTr[ty + 16*a][dg];
                    cP[a] = *(const float4*)&sPc[tx + 16*a][dg];
                    cT[a] = *(const float4*)&sTc[tx + 16*a][dg];
                }
                #pragma unroll
                for (int a = 0; a < 4; ++a)
                    #pragma unroll
                    for (int b = 0; b < 4; ++b)
                        dpp[a][b] += rP[a].x*cP[b].x + rP[a].y*cP[b].y
                                   + rP[a].z*cP[b].z + rP[a].w*cP[b].w;
                #pragma unroll
                for (int a = 0; a < 4; ++a)
                    #pragma unroll
                    for (int b = 0; b < 4; ++b)
                        dpt[a][b] += rP[a].x*cT[b].x + rP[a].y*cT[b].y
                                   + rP[a].z*cT[b].z + rP[a].w*cT[b].w;
                #pragma unroll
                for (int a = 0; a < 4; ++a)
                    #pragma unroll
                    for (int b = 0; b < 4; ++b)
                        dtt[a][b] += rT[a].x*cT[b].x + rT[a].y*cT[b].y
                                   + rT[a].z*cT[b].z + rT[a].w*cT[b].w;
            }
        }

        // epilogue: distances via Gram form, 6-bandwidth RBF sum (masked)
        float total = 0.0f;
        #pragma unroll
        for (int a = 0; a < 4; ++a) {
            const int ii = i0 + ty + 16*a;
            if (ii < n) {
                const float nPi = normP[start + ii];
                const float nTi = normT[start + ii];
                #pragma unroll
                for (int b = 0; b < 4; ++b) {
                    const int jj = j0 + tx + 16*b;
                    if (jj < n) {
                        const float nPj = normP[start + jj];
                        const float nTj = normT[start + jj];
                        float Dpp = nPi + nPj - 2.0f * dpp[a][b];
                        float Dtt = nTi + nTj - 2.0f * dtt[a][b];
                        float Dpt = nPi + nTj - 2.0f * dpt[a][b];
                        #pragma unroll
                        for (int s = 0; s < 6; ++s) {
                            total += __expf(invs[s] * Dpp)
                                   + __expf(invs[s] * Dtt)
                                   - 2.0f * __expf(invs[s] * Dpt);
                        }
                    }
                }
            }
        }

        // wave shuffle reduce (width 64), 4 wave leaders via LDS, 1 atomic
        #pragma unroll
        for (int off = 32; off > 0; off >>= 1)
            total += __shfl_down(total, off, 64);
        if ((t & 63) == 0) wsum[t >> 6] = total;
        __syncthreads();
        if (t == 0)
            atomicAdd(&classSum[c], wsum[0] + wsum[1] + wsum[2] + wsum[3]);
    }
}

// ---------------- Kernel 3: finalize scalar loss ----------------------------
__global__ void finalize_kernel(const int* __restrict__ counts,
                                const float* __restrict__ classSum,
                                float* __restrict__ out) {
    if (threadIdx.x == 0) {
        float loss = 0.0f;
        int k = 0;
        for (int c = 0; c < NCLS; ++c) {
            int n = counts[c];
            if (n > 0) {
                ++k;
                float fn    = (float)n;
                float denom = fmaxf(2.0f * fn * fn, 1.0f);
                float l     = classSum[c] / denom;
                if (l > 0.0f) loss += sqrtf(l);
            }
        }
        out[0] = (k > 0) ? (loss / (float)k) : 0.0f;
    }
}

extern "C" void kernel_launch(void* const* d_in, const int* in_sizes, int n_in,
                              void* d_out, int out_size, void* d_ws, size_t ws_size,
                              hipStream_t stream) {
    const float* predict = (const float*)d_in[0];
    const float* target  = (const float*)d_in[1];
    const int*   gt      = (const int*)d_in[2];
    // d_in[3] = ignore_mask: all-True, unused by the reference math.

    const int V = in_sizes[2];        // B*H*W = 4096
    const int D = in_sizes[0] / V;    // C = 128

    Ctl* ctl = (Ctl*)d_ws;
    size_t normOff = (sizeof(Ctl) + 15) & ~(size_t)15;
    float* normP = (float*)((char*)d_ws + normOff);
    float* normT = normP + V;
    float* classSum = (float*)((char*)d_ws + offsetof(Ctl, classSum));

    int nbNorm = (V + PIXB - 1) / PIXB;
    prep_kernel<<<nbNorm + 1, 256, 0, stream>>>(predict, target, gt, V, D,
                                                ctl, normP, normT, nbNorm);

    mmd_kernel<<<NB, 256, 0, stream>>>(predict, target, V, D, ctl,
                                       normP, normT, classSum);

    finalize_kernel<<<1, 64, 0, stream>>>(ctl->counts, classSum, (float*)d_out);
}

// Round 11
// 100.515 us; speedup vs baseline: 1.0451x; 1.0451x over previous
//
#include <hip/hip_runtime.h>
#include <math.h>

#define NCLS 16
#define TS   64      // pair-tile side (64x64 pairs per work item)
#define CH   32      // D-chunk depth
#define PAD  36      // 144 B row pitch: every row 16B-aligned for ds_read_b128
#define NB   512
#define PIXB 16      // pixels per norm block

// global float4 loads at 4-byte-aligned addresses (class start is arbitrary)
typedef float vfloat4 __attribute__((ext_vector_type(4), aligned(4)));

struct Ctl {
    int   counts[NCLS];
    int   starts[NCLS + 1];
    int   tpc[NCLS];          // tiles per class dimension = ceil(n/TS)
    int   pairBase[NCLS + 1]; // prefix sum of tp*(tp+1)/2 (upper-tri tiles)
    float classSum[NCLS];
};

// ---------------- Kernel 1: norms (16 px/block, 257 blocks) + ctl -----------
// gt is SORTED -> class boundaries via binary search; contiguous segments == classes.
__global__ __launch_bounds__(256) void prep_kernel(
    const float* __restrict__ P, const float* __restrict__ T,
    const int* __restrict__ gt, int V, int D,
    Ctl* __restrict__ ctl,
    float* __restrict__ normP, float* __restrict__ normT,
    int nbNorm) {
    const int b = blockIdx.x;
    const int t = threadIdx.x;
    if (b < nbNorm) {
        __shared__ float pP[16][PIXB + 1], pT[16][PIXB + 1];
        const int pix = t & (PIXB - 1);
        const int dl  = t >> 4;           // 0..15
        const int v   = b * PIXB + pix;
        float np = 0.f, nt = 0.f;
        if (v < V) {
            #pragma unroll 4
            for (int d = dl; d < D; d += 16) {
                float x = P[(long)d * V + v]; np += x * x;
                float y = T[(long)d * V + v]; nt += y * y;
            }
        }
        pP[dl][pix] = np; pT[dl][pix] = nt;
        __syncthreads();
        if (t < PIXB && b * PIXB + t < V) {
            float sp = 0.f, st = 0.f;
            #pragma unroll
            for (int k = 0; k < 16; ++k) { sp += pP[k][t]; st += pT[k][t]; }
            normP[b * PIXB + t] = sp;
            normT[b * PIXB + t] = st;
        }
    } else {
        if (t < NCLS) {
            int lo = 0, hi = V;            // lower_bound of class id t
            while (lo < hi) {
                int mid = (lo + hi) >> 1;
                if (gt[mid] < t) lo = mid + 1; else hi = mid;
            }
            ctl->starts[t] = lo;
            ctl->classSum[t] = 0.0f;       // ws is poisoned 0xAA each replay
        }
        if (t == 0) ctl->starts[NCLS] = V;
        __syncthreads();
        if (t == 0) {
            int pb = 0;
            for (int c = 0; c < NCLS; ++c) {
                int n = ctl->starts[c + 1] - ctl->starts[c];
                ctl->counts[c] = n;
                int tp = (n + TS - 1) / TS;
                ctl->tpc[c] = tp;
                ctl->pairBase[c] = pb;
                pb += tp * (tp + 1) / 2;   // upper-triangular tile pairs only
            }
            ctl->pairBase[NCLS] = pb;
        }
    }
}

// ---------------- Kernel 2: upper-tri 64x64 tiles, 4x4 per thread -----------
// dist(i,j) = n_i + n_j - 2<x_i,x_j>  (Gram form, matches reference numerics).
// R11 symmetry: only tiles ti<=tj. Per element, contribution
//   f * (Kpp + Ktt - Kpt - Ktp),  f = (ti==tj) ? 1 : 2,
// where Ktp uses dtp = <t_i, p_j> (computed from already-staged operands).
// Off-diag: mirrored tile's Kpp/Ktt equal by symmetry, its Kpt equals our Ktp.
// Diag: tile-sum of Ktp equals tile-sum of Kpt, so the formula is exact too.
// Diag tiles alias cols->rows (skip col staging entirely).
// Staging tail rule: quad vector-loaded ONLY if fully inside the class, else
// per-element clamp to pixel n-1 (rows r<n always hold pixel r's data; RBF exp
// amplifies any norm/dot mismatch; rows >= n are masked in the epilogue).
// `#pragma unroll 1` on dc/dg loops bounds the scheduler's hoisting window ->
// no spill (R7/R8 hit 256 VGPR + 60-105 MB scratch under full unroll).
__global__ __launch_bounds__(256) void mmd_kernel(
    const float* __restrict__ P, const float* __restrict__ T,
    int V, int D, const Ctl* __restrict__ ctl,
    const float* __restrict__ normP, const float* __restrict__ normT,
    float* __restrict__ classSum)
{
    __shared__ float sPr[TS][PAD], sTr[TS][PAD];
    __shared__ float sPc[TS][PAD], sTc[TS][PAD];
    __shared__ float wsum[4];

    const int t  = threadIdx.x;
    const int tx = t & 15;   // cols tx + 16b, b=0..3
    const int ty = t >> 4;   // rows ty + 16a, a=0..3
    const int sd = t >> 3;   // staging dim 0..31
    const int qb = t & 7;    // staging pixel-quad base: quads qb and qb+8
    const int W  = ctl->pairBase[NCLS];

    const float invs[6] = {-0.25f, -0.1f, -0.05f, -0.025f, -0.0125f, -1.0f/120.0f};

    for (int w = blockIdx.x; w < W; w += gridDim.x) {
        int c = 0;
        while (ctl->pairBase[c + 1] <= w) ++c;
        const int tp = ctl->tpc[c];
        // triangular decode: row ti has (tp - ti) entries, tj = ti + rem
        int rem = w - ctl->pairBase[c];
        int ti = 0;
        while (rem >= tp - ti) { rem -= (tp - ti); ++ti; }
        const int tj     = ti + rem;
        const bool diag  = (ti == tj);
        const int n      = ctl->counts[c];
        const int start  = ctl->starts[c];
        const int i0     = ti * TS;
        const int j0     = tj * TS;

        // relative quad bases within the class
        const int r0 = i0 + 4 * qb;
        const int r1 = i0 + 4 * qb + 32;
        const int c0 = j0 + 4 * qb;
        const int c1 = j0 + 4 * qb + 32;

        vfloat4 vPr0, vPr1, vTr0, vTr1, vPc0, vPc1, vTc0, vTc1;

        auto load_quad = [&](long off, int rb, vfloat4& vP, vfloat4& vT) {
            if (rb + 3 < n) {
                vP = *(const vfloat4*)&P[off + start + rb];
                vT = *(const vfloat4*)&T[off + start + rb];
            } else {
                int a0 = start + min(rb,     n - 1);
                int a1 = start + min(rb + 1, n - 1);
                int a2 = start + min(rb + 2, n - 1);
                int a3 = start + min(rb + 3, n - 1);
                vP = (vfloat4){P[off + a0], P[off + a1], P[off + a2], P[off + a3]};
                vT = (vfloat4){T[off + a0], T[off + a1], T[off + a2], T[off + a3]};
            }
        };
        auto issue_loads = [&](int dcc) {
            const long off = (long)(dcc + sd) * (long)V;
            load_quad(off, r0, vPr0, vTr0);
            load_quad(off, r1, vPr1, vTr1);
            if (!diag) {
                load_quad(off, c0, vPc0, vTc0);
                load_quad(off, c1, vPc1, vTc1);
            }
        };

        // diag tiles read cols from the row arrays (wave-uniform select)
        const float (*sCp)[PAD] = diag ? sPr : sPc;
        const float (*sCt)[PAD] = diag ? sTr : sTc;

        float dpp[4][4], dtt[4][4], dpt[4][4], dtp[4][4];
        #pragma unroll
        for (int a = 0; a < 4; ++a)
            #pragma unroll
            for (int b = 0; b < 4; ++b)
                { dpp[a][b] = 0.f; dtt[a][b] = 0.f; dpt[a][b] = 0.f; dtp[a][b] = 0.f; }

        issue_loads(0);

        #pragma unroll 1
        for (int dc = 0; dc < D; dc += CH) {
            __syncthreads();   // previous chunk's LDS reads (and wsum) complete
            #pragma unroll
            for (int k = 0; k < 4; ++k) {
                sPr[4*qb +      k][sd] = vPr0[k];
                sPr[4*qb + 32 + k][sd] = vPr1[k];
                sTr[4*qb +      k][sd] = vTr0[k];
                sTr[4*qb + 32 + k][sd] = vTr1[k];
            }
            if (!diag) {
                #pragma unroll
                for (int k = 0; k < 4; ++k) {
                    sPc[4*qb +      k][sd] = vPc0[k];
                    sPc[4*qb + 32 + k][sd] = vPc1[k];
                    sTc[4*qb +      k][sd] = vTc0[k];
                    sTc[4*qb + 32 + k][sd] = vTc1[k];
                }
            }
            __syncthreads();
            if (dc + CH < D)
                issue_loads(dc + CH);   // prefetch next chunk; overlaps compute

            // NOT unrolled; all 16 reads issue before any FMA (one wait point)
            #pragma unroll 1
            for (int dg = 0; dg < CH; dg += 4) {
                float4 rP[4], rT[4], cP[4], cT[4];
                #pragma unroll
                for (int a = 0; a < 4; ++a) {
                    rP[a] = *(const float4*)&sPr[ty + 16*a][dg];
                    rT[a] = *(const float4*)&sTr[ty + 16*a][dg];
                    cP[a] = *(const float4*)&sCp[tx + 16*a][dg];
                    cT[a] = *(const float4*)&sCt[tx + 16*a][dg];
                }
                #pragma unroll
                for (int a = 0; a < 4; ++a)
                    #pragma unroll
                    for (int b = 0; b < 4; ++b)
                        dpp[a][b] += rP[a].x*cP[b].x + rP[a].y*cP[b].y
                                   + rP[a].z*cP[b].z + rP[a].w*cP[b].w;
                #pragma unroll
                for (int a = 0; a < 4; ++a)
                    #pragma unroll
                    for (int b = 0; b < 4; ++b)
                        dpt[a][b] += rP[a].x*cT[b].x + rP[a].y*cT[b].y
                                   + rP[a].z*cT[b].z + rP[a].w*cT[b].w;
                #pragma unroll
                for (int a = 0; a < 4; ++a)
                    #pragma unroll
                    for (int b = 0; b < 4; ++b)
                        dtt[a][b] += rT[a].x*cT[b].x + rT[a].y*cT[b].y
                                   + rT[a].z*cT[b].z + rT[a].w*cT[b].w;
                #pragma unroll
                for (int a = 0; a < 4; ++a)
                    #pragma unroll
                    for (int b = 0; b < 4; ++b)
                        dtp[a][b] += rT[a].x*cP[b].x + rT[a].y*cP[b].y
                                   + rT[a].z*cP[b].z + rT[a].w*cP[b].w;
            }
        }

        // epilogue: distances via Gram form, weighted 4-kernel RBF sum (masked)
        const float f = diag ? 1.0f : 2.0f;
        float total = 0.0f;
        #pragma unroll
        for (int a = 0; a < 4; ++a) {
            const int ii = i0 + ty + 16*a;
            if (ii < n) {
                const float nPi = normP[start + ii];
                const float nTi = normT[start + ii];
                #pragma unroll
                for (int b = 0; b < 4; ++b) {
                    const int jj = j0 + tx + 16*b;
                    if (jj < n) {
                        const float nPj = normP[start + jj];
                        const float nTj = normT[start + jj];
                        float Dpp = nPi + nPj - 2.0f * dpp[a][b];
                        float Dtt = nTi + nTj - 2.0f * dtt[a][b];
                        float Dpt = nPi + nTj - 2.0f * dpt[a][b];
                        float Dtp = nTi + nPj - 2.0f * dtp[a][b];
                        float s6 = 0.0f;
                        #pragma unroll
                        for (int s = 0; s < 6; ++s) {
                            s6 += __expf(invs[s] * Dpp) + __expf(invs[s] * Dtt)
                                - __expf(invs[s] * Dpt) - __expf(invs[s] * Dtp);
                        }
                        total += f * s6;
                    }
                }
            }
        }

        // wave shuffle reduce (width 64), 4 wave leaders via LDS, 1 atomic
        #pragma unroll
        for (int off = 32; off > 0; off >>= 1)
            total += __shfl_down(total, off, 64);
        if ((t & 63) == 0) wsum[t >> 6] = total;
        __syncthreads();
        if (t == 0)
            atomicAdd(&classSum[c], wsum[0] + wsum[1] + wsum[2] + wsum[3]);
    }
}

// ---------------- Kernel 3: finalize scalar loss ----------------------------
__global__ void finalize_kernel(const int* __restrict__ counts,
                                const float* __restrict__ classSum,
                                float* __restrict__ out) {
    if (threadIdx.x == 0) {
        float loss = 0.0f;
        int k = 0;
        for (int c = 0; c < NCLS; ++c) {
            int n = counts[c];
            if (n > 0) {
                ++k;
                float fn    = (float)n;
                float denom = fmaxf(2.0f * fn * fn, 1.0f);
                float l     = classSum[c] / denom;
                if (l > 0.0f) loss += sqrtf(l);
            }
        }
        out[0] = (k > 0) ? (loss / (float)k) : 0.0f;
    }
}

extern "C" void kernel_launch(void* const* d_in, const int* in_sizes, int n_in,
                              void* d_out, int out_size, void* d_ws, size_t ws_size,
                              hipStream_t stream) {
    const float* predict = (const float*)d_in[0];
    const float* target  = (const float*)d_in[1];
    const int*   gt      = (const int*)d_in[2];
    // d_in[3] = ignore_mask: all-True, unused by the reference math.

    const int V = in_sizes[2];        // B*H*W = 4096
    const int D = in_sizes[0] / V;    // C = 128

    Ctl* ctl = (Ctl*)d_ws;
    size_t normOff = (sizeof(Ctl) + 15) & ~(size_t)15;
    float* normP = (float*)((char*)d_ws + normOff);
    float* normT = normP + V;
    float* classSum = (float*)((char*)d_ws + offsetof(Ctl, classSum));

    int nbNorm = (V + PIXB - 1) / PIXB;
    prep_kernel<<<nbNorm + 1, 256, 0, stream>>>(predict, target, gt, V, D,
                                                ctl, normP, normT, nbNorm);

    mmd_kernel<<<NB, 256, 0, stream>>>(predict, target, V, D, ctl,
                                       normP, normT, classSum);

    finalize_kernel<<<1, 64, 0, stream>>>(ctl->counts, classSum, (float*)d_out);
}